// Round 9
// baseline (119.374 us; speedup 1.0000x reference)
//
#include <hip/hip_runtime.h>
#include <cmath>
#include <cstdint>

#define NW       14
#define NST      (1 << NW)      // 16384 amplitudes
#define THREADS  1024
#define PRETHR   768
#define NPASS    12             // layers 1..3 x 4 groups
#define WTP      512            // per-pass W table: TR[256] + TI[256] f16

typedef _Float16 f16;
typedef __fp16   fp16x2 __attribute__((ext_vector_type(2)));
typedef _Float16 f16x8 __attribute__((ext_vector_type(8)));
typedef float    f32x4 __attribute__((ext_vector_type(4)));
typedef unsigned short u16;

// Per-pass XOR-mask addressing: storage = A(phi_p(x)); bank-spread map A
// (GF(2)-linear, identity on bits 0..2, fixes e3) folded into masks host-side.
// State: PLANAR (Re [0,16K), Im [16K,32K) f16). 16 waves/block:
// Mt[2] (4 tiles/wave/pass), Mw[4] (16 wave cosets).
// W tables in GLOBAL (L1/L2-resident) -> W reads on the idle VMEM pipe.
struct PassArg { u16 Mm[4]; u16 Mt[2]; u16 Mw[4]; };
struct Plan { PassArg ps[NPASS]; u16 initM[14]; u16 measR; u16 _pad; };

__device__ __forceinline__ float2 cmulf(float2 a, float2 b) {
    return make_float2(a.x * b.x - a.y * b.y, a.x * b.y + a.y * b.x);
}
// W-table in-block offset with quad-spread (keeps 8-f16 alignment)
__device__ __host__ __forceinline__ unsigned wtofs(unsigned m, unsigned q01) {
    return (m * 16 + q01 * 8) ^ (((m >> 2) & 1u) << 3);
}

// ---------------- pre-kernel: shared tables (angles only) -> d_ws ----------------
__global__ __launch_bounds__(PRETHR)
void vqc_pre(const float* __restrict__ angles, f16* __restrict__ wt_g,
             float2* __restrict__ u0_g)
{
    __shared__ float2 G[4 * NW * 4];
    const int tid = threadIdx.x;

    if (tid < 4 * NW) {
        const int k = tid / NW, w = tid % NW;
        const float a  = angles[(k * NW + w) * 3 + 0];
        const float bb = angles[(k * NW + w) * 3 + 1];
        const float c  = angles[(k * NW + w) * 3 + 2];
        float sa, ca, sb, cb, sc, cc;
        sincosf(a * 0.5f, &sa, &ca);
        sincosf(bb * 0.5f, &sb, &cb);
        sincosf(c * 0.5f, &sc, &cc);
        float2 m00 = make_float2(cb * ca,  sb * sa);
        float2 m01 = make_float2(-sb * ca, -cb * sa);
        float2 m10 = make_float2(sb * ca,  -cb * sa);
        float2 m11 = make_float2(cb * ca,  -sb * sa);
        const float2 e0 = make_float2(cc, -sc), e1 = make_float2(cc, sc);
        const float2 u00 = cmulf(e0, m00), u01 = cmulf(e0, m01);
        const float2 u10 = cmulf(e1, m10), u11 = cmulf(e1, m11);
        const int gi = (k * NW + w) * 4;
        G[gi + 0] = u00; G[gi + 1] = u01; G[gi + 2] = u10; G[gi + 3] = u11;
        if (k == 0) {   // layer-0 STATIC gate (per-sample RY_enc folded in main kernel)
            u0_g[w * 4 + 0] = u00; u0_g[w * 4 + 1] = u01;
            u0_g[w * 4 + 2] = u10; u0_g[w * 4 + 3] = u11;
        }
    }
    __syncthreads();

    // W tables: TR[a'][a] = Re W[a'][a], TI = Im (16x16 per pass), layers 1..3
    {
        const int p = tid >> 6, l6 = tid & 63;
        const int ap = l6 & 15, ahalf = (l6 >> 4) & 1, dup = l6 >> 5;
        const int layer = (p >> 2) + 1, g = p & 3;

        float2 p3;
        if (g == 3) {
            p3 = make_float2((((ap >> 3) & 1) == ahalf) ? 1.f : 0.f, 0.f);
        } else {
            const int wire = 13 - (10 - 4 * g + 3);
            p3 = G[(layer * NW + wire) * 4 + ((ap >> 3) & 1) * 2 + ahalf];
        }
        float2 e0a, e0b, e1a, e1b, e2a, e2b;
        {
            const int r0 = ap & 1, r1 = (ap >> 1) & 1, r2 = (ap >> 2) & 1;
            if (g == 3) {
                const float2* G13 = G + (layer * NW + 13) * 4;
                const float2* G12 = G + (layer * NW + 12) * 4;
                e0a = G13[r0 * 2 + 0]; e0b = G13[r0 * 2 + 1];
                e1a = G12[r1 * 2 + 0]; e1b = G12[r1 * 2 + 1];
                e2a = make_float2(r2 == 0 ? 1.f : 0.f, 0.f);
                e2b = make_float2(r2 == 1 ? 1.f : 0.f, 0.f);
            } else {
                const float2* G0 = G + (layer * NW + (13 - (10 - 4 * g + 0))) * 4;
                const float2* G1 = G + (layer * NW + (13 - (10 - 4 * g + 1))) * 4;
                const float2* G2 = G + (layer * NW + (13 - (10 - 4 * g + 2))) * 4;
                e0a = G0[r0 * 2 + 0]; e0b = G0[r0 * 2 + 1];
                e1a = G1[r1 * 2 + 0]; e1b = G1[r1 * 2 + 1];
                e2a = G2[r2 * 2 + 0]; e2b = G2[r2 * 2 + 1];
            }
        }
        f16x8 frag;
        #pragma unroll
        for (int j2 = 0; j2 < 8; ++j2) {
            float2 v = cmulf(p3, (j2 & 4) ? e2b : e2a);
            v = cmulf(v, (j2 & 2) ? e1b : e1a);
            v = cmulf(v, (j2 & 1) ? e0b : e0a);
            frag[j2] = (f16)(dup ? v.y : v.x);
        }
        *(f16x8*)(wt_g + p * WTP + dup * 256 + wtofs(ap, ahalf)) = frag;
    }
}

// ---------------- main kernel: per-sample, 16 waves ----------------
__global__ __launch_bounds__(THREADS, 4)
void vqc_kernel(const float* __restrict__ x_raw, const f16* __restrict__ wt_g,
                const float2* __restrict__ u0_g, float* __restrict__ out, Plan pl)
{
    extern __shared__ char smem[];
    f16*    Sh  = (f16*)smem;                    // Re [0,16K), Im [16K,32K) f16 (64 KB)
    float2* G0c = (float2*)(Sh + 2 * NST);       // 14 x {col0_row0, col0_row1}
    float*  red = (float*)(G0c + 2 * NW);

    const int b   = blockIdx.x;
    const int tid = threadIdx.x;
    const int lane = tid & 63, wv = tid >> 6;    // wv in [0,16)
    const int q = lane >> 4, m = lane & 15;

    // ---- per-sample layer-0 encode: col0 of U_static * RY_enc(x_w) ----
    if (tid < NW) {
        const float xe = tanhf(x_raw[b * NW + tid]) * 3.14159265358979f;
        float se, ce;
        sincosf(xe * 0.5f, &se, &ce);
        const float2 u00 = u0_g[tid * 4 + 0], u01 = u0_g[tid * 4 + 1];
        const float2 u10 = u0_g[tid * 4 + 2], u11 = u0_g[tid * 4 + 3];
        G0c[tid * 2 + 0] = make_float2(u00.x * ce + u01.x * se, u00.y * ce + u01.y * se);
        G0c[tid * 2 + 1] = make_float2(u10.x * ce + u11.x * se, u10.y * ce + u11.y * se);
    }
    __syncthreads();

    // ---- init: product state (16 amps/thread, 2 chunks of 8) [verified in R3] ----
    // x bits 0..8 <- tid bits 0..8 (wires 13..5); x bit 13 <- tid bit 9 (wire 0);
    // x bits 9..12 <- j (wires 4..1). Identity chain [10]=[9]^1,[11]=[9]^3,
    // [12]=[9]^7 => even-parity j-subsets XOR to {0..7}, odd to t^{0..7}:
    // two 8-aligned chunks; pos->j map linear; runtime low bits fold into
    // factor-pair swaps.
    {
        float2 common = make_float2(1.f, 0.f);
        #pragma unroll
        for (int bit = 0; bit < 9; ++bit) {
            const int w = 13 - bit;
            const float2 f = ((tid >> bit) & 1) ? G0c[w * 2 + 1] : G0c[w * 2 + 0];
            common = cmulf(common, f);
        }
        common = cmulf(common, (tid & 512) ? G0c[0 * 2 + 1] : G0c[0 * 2 + 0]);
        unsigned p10 = 0;
        #pragma unroll
        for (int bit = 0; bit < 9; ++bit)
            p10 ^= ((tid >> bit) & 1) ? (unsigned)pl.initM[bit] : 0u;
        if (tid & 512) p10 ^= (unsigned)pl.initM[13];
        const unsigned t9 = (unsigned)pl.initM[9];

        const float2 w4a = G0c[4*2+0], w4b = G0c[4*2+1];   // x9  -> wire 4
        const float2 w3a = G0c[3*2+0], w3b = G0c[3*2+1];   // x10 -> wire 3
        const float2 w2a = G0c[2*2+0], w2b = G0c[2*2+1];   // x11 -> wire 2
        const float2 w1a = G0c[1*2+0], w1b = G0c[1*2+1];   // x12 -> wire 1

        #pragma unroll
        for (int c = 0; c < 2; ++c) {
            const unsigned ac = p10 ^ (c ? t9 : 0u);
            const unsigned r = ac & 7u;
            const unsigned base = ac & ~7u;
            const bool sA = ((r ^ (unsigned)c) & 1u) != 0;          // x9  swap: r0^c
            const bool sB = ((r ^ (r >> 1)) & 1u) != 0;             // r0^r1
            const bool sC = (((r >> 1) ^ (r >> 2)) & 1u) != 0;      // r1^r2
            const bool sD = ((r >> 2) & 1u) != 0;                   // r2
            const float2 A_[2] = { sA ? w4b : w4a, sA ? w4a : w4b };
            const float2 B_[2] = { sB ? w3b : w3a, sB ? w3a : w3b };
            const float2 C_[2] = { sC ? w2b : w2a, sC ? w2a : w2b };
            const float2 D_[2] = { sD ? w1b : w1a, sD ? w1a : w1b };
            const float2 U0  = cmulf(common, A_[0]), U1  = cmulf(common, A_[1]);
            const float2 W00 = cmulf(U0, B_[0]),     W01 = cmulf(U0, B_[1]);
            const float2 W10 = cmulf(U1, B_[1]),     W11 = cmulf(U1, B_[0]);
            const float2 V00 = cmulf(C_[0], D_[0]),  V01 = cmulf(C_[1], D_[1]);
            const float2 V10 = cmulf(C_[1], D_[0]),  V11 = cmulf(C_[0], D_[1]);
            union { f16 h[8]; f16x8 v; } hR, hI;
            float2 amp;
            amp = cmulf(W00, V00); hR.h[0] = (f16)amp.x; hI.h[0] = (f16)amp.y;
            amp = cmulf(W10, V00); hR.h[1] = (f16)amp.x; hI.h[1] = (f16)amp.y;
            amp = cmulf(W01, V10); hR.h[2] = (f16)amp.x; hI.h[2] = (f16)amp.y;
            amp = cmulf(W11, V10); hR.h[3] = (f16)amp.x; hI.h[3] = (f16)amp.y;
            amp = cmulf(W00, V01); hR.h[4] = (f16)amp.x; hI.h[4] = (f16)amp.y;
            amp = cmulf(W10, V01); hR.h[5] = (f16)amp.x; hI.h[5] = (f16)amp.y;
            amp = cmulf(W01, V11); hR.h[6] = (f16)amp.x; hI.h[6] = (f16)amp.y;
            amp = cmulf(W11, V11); hR.h[7] = (f16)amp.x; hI.h[7] = (f16)amp.y;
            *(f16x8*)(Sh + base)       = hR.v;
            *(f16x8*)(Sh + NST + base) = hI.v;
        }
    }
    __syncthreads();

    // ---- 12 MFMA passes, in-place, ONE barrier per pass ----
    // A wave's read and write sets are the SAME wave-private coset
    //   wb ^ span{1,2,4,8, Mm[0..3], Mt[0..1]}  (10-dim; 16 Mw cosets disjoint),
    // and per-wave DS ops execute in order -> no mid-pass barrier needed.
    // W from GLOBAL (VMEM pipe); Re/Im writes fused via ds_write2st64_b64.
    const unsigned plane_off = (unsigned)(q >> 1) << 14;
    const unsigned q01 = (unsigned)(q & 1);
    const f16* wbase = wt_g + wtofs((unsigned)m, q01);
    const f32x4 z4 = {0.f, 0.f, 0.f, 0.f};
    #pragma unroll
    for (int p = 0; p < NPASS; ++p) {
        const PassArg& P = pl.ps[p];
        const unsigned pm = ((m & 1) ? P.Mm[0] : 0) ^ ((m & 2) ? P.Mm[1] : 0)
                          ^ ((m & 4) ? P.Mm[2] : 0) ^ ((m & 8) ? P.Mm[3] : 0);
        const unsigned wb = ((wv & 1) ? P.Mw[0] : 0) ^ ((wv & 2) ? P.Mw[1] : 0)
                          ^ ((wv & 4) ? P.Mw[2] : 0) ^ ((wv & 8) ? P.Mw[3] : 0);
        const unsigned b0 = pm ^ wb;
        const f16x8 tr = *(const f16x8*)(wbase + p * WTP);
        const f16x8 ti = *(const f16x8*)(wbase + p * WTP + 256);
        const f16x8 bf1 = (q < 2) ? tr : -ti;   // [Wr' ; -Wi']
        const f16x8 bf2 = (q < 2) ? ti : tr;    // [Wi' ;  Wr']
        unsigned sw[4];
        f16x8 av[4];
        #pragma unroll
        for (int tt = 0; tt < 4; ++tt) {
            sw[tt] = b0 ^ ((tt & 1) ? P.Mt[0] : 0)
                        ^ ((tt & 2) ? P.Mt[1] : 0);
            av[tt] = *(const f16x8*)(Sh + plane_off + (sw[tt] ^ (q01 << 3)));
        }
        #pragma unroll
        for (int tt = 0; tt < 4; ++tt) {
            const f32x4 d1 = __builtin_amdgcn_mfma_f32_16x16x32_f16(av[tt], bf1, z4, 0, 0, 0);
            const f32x4 d2 = __builtin_amdgcn_mfma_f32_16x16x32_f16(av[tt], bf2, z4, 0, 0, 0);
            union { fp16x2 h2[2]; unsigned long long u; } c1, c2;
            c1.h2[0] = __builtin_amdgcn_cvt_pkrtz(d1[0], d1[1]);
            c1.h2[1] = __builtin_amdgcn_cvt_pkrtz(d1[2], d1[3]);
            c2.h2[0] = __builtin_amdgcn_cvt_pkrtz(d2[0], d2[1]);
            c2.h2[1] = __builtin_amdgcn_cvt_pkrtz(d2[2], d2[3]);
            const unsigned wu = sw[tt] ^ ((unsigned)q << 2);
            const unsigned lds_addr = (unsigned)(uintptr_t)(Sh + wu);
            // Re plane at +0, Im plane at +64*512B = +32768B = +NST f16
            asm volatile("ds_write2st64_b64 %0, %1, %2 offset0:0 offset1:64"
                         :: "v"(lds_addr), "v"(c1.u), "v"(c2.u) : "memory");
        }
        __syncthreads();
    }

    // ---- <Z_0>: conflict-free (wave reads 1 KiB contiguous per b128) ----
    float acc = 0.f;
    {
        #pragma unroll
        for (int cch = 0; cch < 2; ++cch) {
            const unsigned addr = (unsigned)cch * 8192u + (unsigned)tid * 8u;  // = position
            const f16x8 rr = *(const f16x8*)(Sh + addr);
            const f16x8 ii = *(const f16x8*)(Sh + NST + addr);
            const int pb = __popc(addr & (unsigned)pl.measR) & 1;
            #pragma unroll
            for (int e = 0; e < 8; ++e) {
                const float re = (float)rr[e], im = (float)ii[e];
                const float pw = fmaf(re, re, im * im);
                const int sgn = pb ^ (__popc((unsigned)e & (unsigned)pl.measR) & 1);
                acc += sgn ? -pw : pw;
            }
        }
    }
    #pragma unroll
    for (int off = 32; off > 0; off >>= 1) acc += __shfl_down(acc, off);
    if ((tid & 63) == 0) red[wv] = acc;
    __syncthreads();
    if (tid == 0) {
        float s = 0.f;
        #pragma unroll
        for (int i = 0; i < THREADS / 64; ++i) s += red[i];
        out[b] = s;
    }
}

// ---------------- host-side GF(2) layout scheduling ----------------
struct GFm { u16 col[14]; };   // col[b] = image of e_b

static unsigned ringp_host(unsigned x) {
    unsigned s = x;
    s ^= s >> 1; s ^= s >> 2; s ^= s >> 4; s ^= s >> 8;
    s &= 0x3FFFu;
    return (s ^ ((s & 1u) << 13)) & 0x3FFFu;
}
static u16 gf_apply(const GFm& m, u16 v) {
    u16 r = 0;
    for (int b = 0; b < 14; ++b) if ((v >> b) & 1) r ^= m.col[b];
    return r;
}
static GFm gf_compose(const GFm& A, const GFm& B) {
    GFm C;
    for (int b = 0; b < 14; ++b) C.col[b] = gf_apply(A, B.col[b]);
    return C;
}
static void rows_from(const GFm& A, u16 r[14]) {
    for (int i = 0; i < 14; ++i) {
        u16 mm = 0;
        for (int b = 0; b < 14; ++b) mm |= (u16)(((A.col[b] >> i) & 1) << b);
        r[i] = mm;
    }
}
static GFm from_rows(const u16 r[14]) {
    GFm A;
    for (int b = 0; b < 14; ++b) {
        u16 c = 0;
        for (int i = 0; i < 14; ++i) c |= (u16)(((r[i] >> b) & 1) << i);
        A.col[b] = c;
    }
    return A;
}
static GFm gf_inv(const GFm& A) {
    u16 M[14], I[14];
    rows_from(A, M);
    for (int i = 0; i < 14; ++i) I[i] = (u16)(1u << i);
    for (int c = 0; c < 14; ++c) {
        int p = c;
        while (p < 14 && !((M[p] >> c) & 1)) ++p;
        if (p == 14) continue;
        u16 t = M[c]; M[c] = M[p]; M[p] = t;
        t = I[c]; I[c] = I[p]; I[p] = t;
        for (int r2 = 0; r2 < 14; ++r2)
            if (r2 != c && ((M[r2] >> c) & 1)) { M[r2] ^= M[c]; I[r2] ^= I[c]; }
    }
    return from_rows(I);
}

static void build_plan(Plan& pl) {
    GFm ring, ringInv;
    for (int b = 0; b < 14; ++b) ring.col[b] = (u16)ringp_host(1u << b);
    ringInv = gf_inv(ring);

    GFm phi;
    for (int j = 0; j < 4; ++j) phi.col[10 + j] = (u16)(1u << j);
    for (int j = 0; j < 4; ++j) phi.col[6 + j]  = (u16)(1u << (4 + j));
    for (int j = 0; j < 4; ++j) phi.col[2 + j]  = (u16)(1u << (8 + j));
    phi.col[0] = (u16)(1u << 12);
    phi.col[1] = (u16)(1u << 13);

    for (int b = 0; b < 14; ++b) pl.initM[b] = gf_apply(phi, ring.col[b]);

    const int gb[4][4] = {{10,11,12,13},{6,7,8,9},{2,3,4,5},{0,1,6,7}};

    for (int p = 0; p < NPASS; ++p) {
        const int g = p & 3;
        u16 uv[4];
        if (g < 3) for (int j = 0; j < 4; ++j) uv[j] = (u16)(1u << gb[g + 1][j]);
        else       for (int j = 0; j < 4; ++j) uv[j] = ringInv.col[10 + j];
        for (int j = 0; j < 4; ++j) pl.ps[p].Mm[j] = gf_apply(phi, uv[j]);

        u16 span[14]; int ns = 0;
        u16 tv[6]; int nt = 0;
        auto tryAdd = [&](u16 v) -> bool {
            bool ch = true;
            while (ch) {
                ch = false;
                for (int i = 0; i < ns; ++i) {
                    const int tb = 31 - __builtin_clz((unsigned)span[i]);
                    if ((v >> tb) & 1) { v ^= span[i]; ch = true; }
                }
            }
            if (!v) return false;
            span[ns++] = v;
            return true;
        };
        for (int j = 0; j < 4; ++j) tryAdd((u16)(1u << gb[g][j]));
        for (int j = 0; j < 4; ++j) tryAdd(uv[j]);
        for (int b2 = 0; b2 < 14 && nt < 6; ++b2)
            if (tryAdd((u16)(1u << b2))) tv[nt++] = (u16)(1u << b2);
        for (int i = 0; i < 2; ++i) pl.ps[p].Mt[i] = gf_apply(phi, tv[i]);      // tile (4)
        for (int i = 0; i < 4; ++i) pl.ps[p].Mw[i] = gf_apply(phi, tv[i + 2]);  // wave (16)

        GFm Bm;
        for (int j = 0; j < 4; ++j) Bm.col[j]     = (u16)(1u << gb[g][j]);
        for (int j = 0; j < 4; ++j) Bm.col[4 + j] = uv[j];
        for (int i = 0; i < 6; ++i) Bm.col[8 + i] = tv[i];
        GFm Binv = gf_inv(Bm);
        u16 img[14];
        for (int j = 0; j < 4; ++j) img[j]     = pl.ps[p].Mm[j];
        for (int j = 0; j < 4; ++j) img[4 + j] = (u16)(1u << j);
        for (int i = 0; i < 6; ++i) img[8 + i] = gf_apply(phi, tv[i]);
        GFm nphi;
        for (int b2 = 0; b2 < 14; ++b2) {
            const u16 coef = gf_apply(Binv, (u16)(1u << b2));
            u16 v = 0;
            for (int j = 0; j < 14; ++j) if ((coef >> j) & 1) v ^= img[j];
            nphi.col[b2] = v;
        }
        if (g == 3) nphi = gf_compose(nphi, ringInv);
        phi = nphi;
    }

    GFm pinv = gf_inv(phi);
    u16 rows[14];
    rows_from(pinv, rows);
    pl.measR = rows[13];
    pl._pad = 0;
}

// ---- bank-spread map A: out[3:5] = M*s[3:5] ^ L*s[6:13], identity elsewhere.
// Constraints: M invertible, M*e3 = e3 (preserves init-chunk identity + alignment).
struct SwzP { unsigned c4, c5; unsigned char Lc[8]; };

static unsigned proj35(const SwzP& s, u16 v) {
    unsigned a = ((unsigned)v >> 3) & 7u;
    unsigned r = (a & 1u) ? 1u : 0u;          // col for input bit3 = e3
    if (a & 2u) r ^= s.c4;
    if (a & 4u) r ^= s.c5;
    unsigned hb = ((unsigned)v >> 6) & 0xFFu;
    for (int c = 0; c < 8; ++c) if ((hb >> c) & 1u) r ^= s.Lc[c];
    return r & 7u;
}
static int rank3(const unsigned* q, int n) {
    unsigned bas[3] = {0, 0, 0};
    int r = 0;
    for (int j = 0; j < n; ++j) {
        unsigned v = q[j];
        for (int bit = 2; bit >= 0; --bit) {
            if (!((v >> bit) & 1u)) continue;
            if (bas[bit]) { v ^= bas[bit]; continue; }
            bas[bit] = v; ++r; v = 0; break;
        }
    }
    return r;
}
static bool minv_ok(unsigned c4, unsigned c5) {  // {e0, c4, c5} rank 3
    const unsigned q[3] = {1u, c4 & 7u, c5 & 7u};
    return rank3(q, 3) == 3;
}
static int score_swz(const SwzP& s, const u16 MmRaw[NPASS][4]) {
    int bad = 0;
    for (int p = 0; p < NPASS; ++p) {
        unsigned q[4];
        for (int j = 0; j < 4; ++j) q[j] = proj35(s, MmRaw[p][j]);
        bad += 3 - rank3(q, 4);
    }
    return bad;
}
static GFm A_from(const SwzP& s) {
    GFm A;
    for (int b = 0; b < 14; ++b) A.col[b] = (u16)(1u << b);
    A.col[4] = (u16)((s.c4 & 7u) << 3);
    A.col[5] = (u16)((s.c5 & 7u) << 3);
    for (int c = 0; c < 8; ++c)
        A.col[6 + c] = (u16)((1u << (6 + c)) ^ (((unsigned)s.Lc[c] & 7u) << 3));
    return A;
}
static void choose_swz(const Plan& raw, GFm& A, GFm& Ainv) {
    u16 MmRaw[NPASS][4];
    for (int p = 0; p < NPASS; ++p)
        for (int j = 0; j < 4; ++j) MmRaw[p][j] = raw.ps[p].Mm[j];

    // candidate 0 = the long-standing fixed hash (baseline)
    SwzP best = {2u, 4u, {1, 2, 4, 1, 2, 5, 2, 4}};
    int bestScore = score_swz(best, MmRaw);

    uint64_t rng = 0x9E3779B97F4A7C15ull;
    auto rnd = [&]() -> unsigned {
        rng = rng * 6364136223846793005ull + 1442695040888963407ull;
        return (unsigned)(rng >> 33);
    };
    for (int t = 0; t < 8000 && bestScore > 0; ++t) {
        SwzP s;
        s.c4 = rnd() & 7u; s.c5 = rnd() & 7u;
        if (!minv_ok(s.c4, s.c5)) continue;
        for (int c = 0; c < 8; ++c) s.Lc[c] = (unsigned char)(rnd() & 7u);
        const int sc = score_swz(s, MmRaw);
        if (sc < bestScore) { bestScore = sc; best = s; }
    }
    A = A_from(best);
    Ainv = gf_inv(A);
}
static void fold_A(Plan& pl, const GFm& A, const GFm& Ainv) {
    for (int p = 0; p < NPASS; ++p) {
        for (int j = 0; j < 4; ++j) pl.ps[p].Mm[j] = gf_apply(A, pl.ps[p].Mm[j]);
        for (int j = 0; j < 2; ++j) pl.ps[p].Mt[j] = gf_apply(A, pl.ps[p].Mt[j]);
        for (int j = 0; j < 4; ++j) pl.ps[p].Mw[j] = gf_apply(A, pl.ps[p].Mw[j]);
    }
    for (int b = 0; b < 14; ++b) pl.initM[b] = gf_apply(A, pl.initM[b]);
    // sign(storage s) = parity(r . logical), logical = Ainv(s)
    //   => measR'_b = parity(r & Ainv.col[b])
    const unsigned r = pl.measR;
    u16 nr = 0;
    for (int b = 0; b < 14; ++b)
        if (__builtin_popcount(r & (unsigned)Ainv.col[b]) & 1) nr |= (u16)(1u << b);
    pl.measR = nr;
}

extern "C" void kernel_launch(void* const* d_in, const int* in_sizes, int n_in,
                              void* d_out, int out_size, void* d_ws, size_t ws_size,
                              hipStream_t stream) {
    const float* x_raw  = (const float*)d_in[0];
    const float* angles = (const float*)d_in[1];
    float* out = (float*)d_out;
    const int bsz = in_sizes[0] / NW;

    Plan pl;
    build_plan(pl);
    GFm A, Ainv;
    choose_swz(pl, A, Ainv);
    fold_A(pl, A, Ainv);

    // d_ws layout: [0,12288) W tables (f16), [12288,12736) layer-0 static gates
    f16*    wt_g = (f16*)d_ws;
    float2* u0_g = (float2*)((char*)d_ws + (size_t)NPASS * WTP * sizeof(f16));

    vqc_pre<<<dim3(1), dim3(PRETHR), 0, stream>>>(angles, wt_g, u0_g);

    // LDS: 64K state + 224B G0c + 64B red = 65824 B -> 2 blocks/CU, 32 waves/CU
    const size_t lds = (size_t)2 * NST * sizeof(f16)
                     + (size_t)(2 * NW) * sizeof(float2)
                     + (size_t)(THREADS / 64) * sizeof(float);
    (void)hipFuncSetAttribute((const void*)vqc_kernel,
                              hipFuncAttributeMaxDynamicSharedMemorySize, (int)lds);
    vqc_kernel<<<dim3(bsz), dim3(THREADS), lds, stream>>>(x_raw, wt_g, u0_g, out, pl);
}

// Round 10
// 106.590 us; speedup vs baseline: 1.1199x; 1.1199x over previous
//
#include <hip/hip_runtime.h>
#include <cmath>
#include <cstdint>

#define NW       14
#define NST      (1 << NW)      // 16384 amplitudes
#define THREADS  512
#define PRETHR   768
#define NPASS    12             // layers 1..3 x 4 groups
#define WTP      512            // per-pass W table: TR[256] + TI[256] f16

typedef _Float16 f16;
typedef __fp16   fp16x2 __attribute__((ext_vector_type(2)));
typedef _Float16 f16x8 __attribute__((ext_vector_type(8)));
typedef float    f32x4 __attribute__((ext_vector_type(4)));
typedef unsigned short u16;

// Per-pass XOR-mask addressing: storage = A(phi_p(x)); the bank-spread map A
// (GF(2)-linear, identity on bits 0..2, fixes e3) is folded into all masks
// HOST-side. State layout: PLANAR (Re [0,16K), Im [16K,32K) f16) -- reads
// spread pos bits 3..5 rank-3 over bank groups (2 lanes/group, free).
// W tables live in GLOBAL (L1/L2-resident), duplicated per q-half with signs
// PRE-FOLDED: qh=0 -> [TR, TI], qh=1 -> [-TI, TR]. Each lane loads its
// (bf1, bf2) directly -- no per-pass selects/negation on the VALU.
struct PassArg { u16 Mm[4]; u16 Mt[3]; u16 Mw[3]; };
struct Plan { PassArg ps[NPASS]; u16 initM[14]; u16 measR; u16 _pad; };

__device__ __forceinline__ float2 cmulf(float2 a, float2 b) {
    return make_float2(a.x * b.x - a.y * b.y, a.x * b.y + a.y * b.x);
}
// W-table in-block offset with quad-spread (keeps 8-f16 alignment)
__device__ __host__ __forceinline__ unsigned wtofs(unsigned m, unsigned q01) {
    return (m * 16 + q01 * 8) ^ (((m >> 2) & 1u) << 3);
}

// ---------------- pre-kernel: shared tables (angles only) -> d_ws ----------------
__global__ __launch_bounds__(PRETHR)
void vqc_pre(const float* __restrict__ angles, f16* __restrict__ wt_g,
             float2* __restrict__ u0_g)
{
    __shared__ float2 G[4 * NW * 4];
    const int tid = threadIdx.x;

    if (tid < 4 * NW) {
        const int k = tid / NW, w = tid % NW;
        const float a  = angles[(k * NW + w) * 3 + 0];
        const float bb = angles[(k * NW + w) * 3 + 1];
        const float c  = angles[(k * NW + w) * 3 + 2];
        float sa, ca, sb, cb, sc, cc;
        sincosf(a * 0.5f, &sa, &ca);
        sincosf(bb * 0.5f, &sb, &cb);
        sincosf(c * 0.5f, &sc, &cc);
        float2 m00 = make_float2(cb * ca,  sb * sa);
        float2 m01 = make_float2(-sb * ca, -cb * sa);
        float2 m10 = make_float2(sb * ca,  -cb * sa);
        float2 m11 = make_float2(cb * ca,  -sb * sa);
        const float2 e0 = make_float2(cc, -sc), e1 = make_float2(cc, sc);
        const float2 u00 = cmulf(e0, m00), u01 = cmulf(e0, m01);
        const float2 u10 = cmulf(e1, m10), u11 = cmulf(e1, m11);
        const int gi = (k * NW + w) * 4;
        G[gi + 0] = u00; G[gi + 1] = u01; G[gi + 2] = u10; G[gi + 3] = u11;
        if (k == 0) {   // layer-0 STATIC gate (per-sample RY_enc folded in main kernel)
            u0_g[w * 4 + 0] = u00; u0_g[w * 4 + 1] = u01;
            u0_g[w * 4 + 2] = u10; u0_g[w * 4 + 3] = u11;
        }
    }
    __syncthreads();

    // W tables: TR[a'][a] = Re W[a'][a], TI = Im (16x16 per pass), layers 1..3
    {
        const int p = tid >> 6, l6 = tid & 63;
        const int ap = l6 & 15, ahalf = (l6 >> 4) & 1, dup = l6 >> 5;
        const int layer = (p >> 2) + 1, g = p & 3;

        float2 p3;
        if (g == 3) {
            p3 = make_float2((((ap >> 3) & 1) == ahalf) ? 1.f : 0.f, 0.f);
        } else {
            const int wire = 13 - (10 - 4 * g + 3);
            p3 = G[(layer * NW + wire) * 4 + ((ap >> 3) & 1) * 2 + ahalf];
        }
        float2 e0a, e0b, e1a, e1b, e2a, e2b;
        {
            const int r0 = ap & 1, r1 = (ap >> 1) & 1, r2 = (ap >> 2) & 1;
            if (g == 3) {
                const float2* G13 = G + (layer * NW + 13) * 4;
                const float2* G12 = G + (layer * NW + 12) * 4;
                e0a = G13[r0 * 2 + 0]; e0b = G13[r0 * 2 + 1];
                e1a = G12[r1 * 2 + 0]; e1b = G12[r1 * 2 + 1];
                e2a = make_float2(r2 == 0 ? 1.f : 0.f, 0.f);
                e2b = make_float2(r2 == 1 ? 1.f : 0.f, 0.f);
            } else {
                const float2* G0 = G + (layer * NW + (13 - (10 - 4 * g + 0))) * 4;
                const float2* G1 = G + (layer * NW + (13 - (10 - 4 * g + 1))) * 4;
                const float2* G2 = G + (layer * NW + (13 - (10 - 4 * g + 2))) * 4;
                e0a = G0[r0 * 2 + 0]; e0b = G0[r0 * 2 + 1];
                e1a = G1[r1 * 2 + 0]; e1b = G1[r1 * 2 + 1];
                e2a = G2[r2 * 2 + 0]; e2b = G2[r2 * 2 + 1];
            }
        }
        f16x8 frag;
        #pragma unroll
        for (int j2 = 0; j2 < 8; ++j2) {
            float2 v = cmulf(p3, (j2 & 4) ? e2b : e2a);
            v = cmulf(v, (j2 & 2) ? e1b : e1a);
            v = cmulf(v, (j2 & 1) ? e0b : e0a);
            frag[j2] = (f16)(dup ? v.y : v.x);
        }
        const unsigned ofs = wtofs(ap, ahalf);
        // q-half 0: [TR | TI]  (dup=0 -> slot A, dup=1 -> slot B)
        *(f16x8*)(wt_g + p * WTP + dup * 256 + ofs) = frag;
        // q-half 1: [-TI | TR] (dup=1 -> slot A negated, dup=0 -> slot B)
        const f16x8 nfrag = dup ? -frag : frag;
        *(f16x8*)(wt_g + NPASS * WTP + p * WTP + (dup ? 0 : 256) + ofs) = nfrag;
    }
}

// ---------------- main kernel: per-sample ----------------
__global__ __launch_bounds__(THREADS, 4)
void vqc_kernel(const float* __restrict__ x_raw, const f16* __restrict__ wt_g,
                const float2* __restrict__ u0_g, float* __restrict__ out, Plan pl)
{
    extern __shared__ char smem[];
    f16*    Sh  = (f16*)smem;                    // Re [0,16K), Im [16K,32K) f16 (64 KB)
    float2* G0c = (float2*)(Sh + 2 * NST);       // 14 x {col0_row0, col0_row1}
    float*  red = (float*)(G0c + 2 * NW);

    const int b   = blockIdx.x;
    const int tid = threadIdx.x;
    const int lane = tid & 63, wv = tid >> 6;
    const int q = lane >> 4, m = lane & 15;

    // ---- per-sample layer-0 encode: col0 of U_static * RY_enc(x_w) ----
    if (tid < NW) {
        const float xe = tanhf(x_raw[b * NW + tid]) * 3.14159265358979f;
        float se, ce;
        sincosf(xe * 0.5f, &se, &ce);
        const float2 u00 = u0_g[tid * 4 + 0], u01 = u0_g[tid * 4 + 1];
        const float2 u10 = u0_g[tid * 4 + 2], u11 = u0_g[tid * 4 + 3];
        G0c[tid * 2 + 0] = make_float2(u00.x * ce + u01.x * se, u00.y * ce + u01.y * se);
        G0c[tid * 2 + 1] = make_float2(u10.x * ce + u11.x * se, u10.y * ce + u11.y * se);
    }
    __syncthreads();

    // ---- init: product state after all layer-0 1q gates ----
    // Key identity (A fixes e0..e3, identity on bits 0..2):
    //   initM[9]^initM[10]=1, [10]^[11]=2, [11]^[12]=4, [12]^[13]=8.
    // Each thread's 32 amps land in exactly TWO aligned 16-elem chunks.
    {
        float2 common = make_float2(1.f, 0.f);
        #pragma unroll
        for (int bit = 0; bit < 9; ++bit) {          // x bits 0..8 from tid (wires 13..5)
            const int w = 13 - bit;
            const float2 f = ((tid >> bit) & 1) ? G0c[w * 2 + 1] : G0c[w * 2 + 0];
            common = cmulf(common, f);
        }
        unsigned p9 = 0;
        #pragma unroll
        for (int bit = 0; bit < 9; ++bit)
            p9 ^= ((tid >> bit) & 1) ? (unsigned)pl.initM[bit] : 0u;

        const float2 f0a = G0c[4*2+0], f0b = G0c[4*2+1];   // j bit0 -> wire 4
        const float2 f1a = G0c[3*2+0], f1b = G0c[3*2+1];
        const float2 f2a = G0c[2*2+0], f2b = G0c[2*2+1];
        const float2 f3a = G0c[1*2+0], f3b = G0c[1*2+1];
        const float2 f4a = G0c[0*2+0], f4b = G0c[0*2+1];   // j bit4 -> wire 0

        const unsigned S   = (unsigned)pl.initM[13];
        const unsigned Slo = S & 15u, Hh = S & ~15u;
        const unsigned plo = p9 & 15u, B0 = p9 & ~15u;

        #pragma unroll
        for (int c = 0; c < 2; ++c) {
            const unsigned r = plo ^ (c ? Slo : 0u);
            const bool s0 = ((r       ) & 1u) != 0;                    // o0 ^ r0
            const bool s1 = (((r) ^ (r >> 1)) & 1u) != 0;              // (o0^o1) ^ (r0^r1)
            const bool s2 = (((r >> 1) ^ (r >> 2)) & 1u) != 0;
            const bool s3 = (((r >> 2) ^ (r >> 3)) & 1u) != 0;
            const bool s4 = ((((r >> 3) & 1u) ^ (unsigned)c) != 0);    // o3 ^ (r3^c)
            const float2 F0[2] = { s0 ? f0b : f0a, s0 ? f0a : f0b };
            const float2 F1[2] = { s1 ? f1b : f1a, s1 ? f1a : f1b };
            const float2 F2[2] = { s2 ? f2b : f2a, s2 ? f2a : f2b };
            const float2 F3[2] = { s3 ? f3b : f3a, s3 ? f3a : f3b };
            const float2 F4[2] = { s4 ? f4b : f4a, s4 ? f4a : f4b };
            // amp(c,o) = common * F4[o3] * F3[o2^o3] * F2[o1^o2] * F1[o0^o1] * F0[o0]
            const float2 A0 = cmulf(common, F4[0]);
            const float2 A1 = cmulf(common, F4[1]);
            float2 Bt[4];                         // [o3*2+o2] = A[o3]*F3[o2^o3]
            Bt[0] = cmulf(A0, F3[0]); Bt[1] = cmulf(A0, F3[1]);
            Bt[2] = cmulf(A1, F3[1]); Bt[3] = cmulf(A1, F3[0]);
            float2 Ct[8];                         // [(o3o2)*2+o1] = Bt*F2[o1^o2]
            #pragma unroll
            for (int o32 = 0; o32 < 4; ++o32) {
                const int o2 = o32 & 1;
                Ct[o32 * 2 + 0] = cmulf(Bt[o32], F2[o2]);
                Ct[o32 * 2 + 1] = cmulf(Bt[o32], F2[1 ^ o2]);
            }
            float2 Gt[4];                         // [o1*2+o0] = F1[o0^o1]*F0[o0]
            Gt[0] = cmulf(F1[0], F0[0]); Gt[1] = cmulf(F1[1], F0[1]);
            Gt[2] = cmulf(F1[1], F0[0]); Gt[3] = cmulf(F1[0], F0[1]);

            union { f16 h[8]; f16x8 v; } hR[2], hI[2];
            #pragma unroll
            for (int o = 0; o < 16; ++o) {
                const int o0 = o & 1, o1 = (o >> 1) & 1;
                const float2 amp = cmulf(Ct[o >> 1], Gt[o1 * 2 + o0]);
                hR[o >> 3].h[o & 7] = (f16)amp.x;
                hI[o >> 3].h[o & 7] = (f16)amp.y;
            }
            const unsigned bb = B0 ^ (c ? Hh : 0u);   // 16-elem (32 B) aligned
            *(f16x8*)(Sh + bb)           = hR[0].v;
            *(f16x8*)(Sh + bb + 8)       = hR[1].v;
            *(f16x8*)(Sh + NST + bb)     = hI[0].v;
            *(f16x8*)(Sh + NST + bb + 8) = hI[1].v;
        }
    }
    __syncthreads();

    // ---- 12 MFMA passes, in-place, ONE barrier per pass ----
    // A wave's read and write sets are the SAME wave-private coset
    //   wb ^ span{1,2,4,8, Mm[0..3], Mt[0..2]}  (Mw cosets disjoint),
    // and per-wave DS ops execute in order -> no mid-pass barrier needed.
    // (bf1,bf2) read directly from the per-q-half pre-negated GLOBAL W table
    // (VMEM pipe; unrolled loop lets the compiler prefetch ahead).
    // Re/Im plane writes fused: ds_write2st64_b64 offset1:64 (= +32768 B).
    const unsigned plane_off = (unsigned)(q >> 1) << 14;
    const unsigned q01 = (unsigned)(q & 1);
    const f16* wbase = wt_g + (unsigned)(q >> 1) * (NPASS * WTP)
                            + wtofs((unsigned)m, q01);
    const f32x4 z4 = {0.f, 0.f, 0.f, 0.f};
    #pragma unroll
    for (int p = 0; p < NPASS; ++p) {
        const PassArg& P = pl.ps[p];
        const unsigned pm = ((m & 1) ? P.Mm[0] : 0) ^ ((m & 2) ? P.Mm[1] : 0)
                          ^ ((m & 4) ? P.Mm[2] : 0) ^ ((m & 8) ? P.Mm[3] : 0);
        const unsigned wb = ((wv & 1) ? P.Mw[0] : 0) ^ ((wv & 2) ? P.Mw[1] : 0)
                          ^ ((wv & 4) ? P.Mw[2] : 0);
        const unsigned b0 = pm ^ wb;
        const f16x8 bf1 = *(const f16x8*)(wbase + p * WTP);         // q<2: Wr ; q>=2: -Wi
        const f16x8 bf2 = *(const f16x8*)(wbase + p * WTP + 256);   // q<2: Wi ; q>=2:  Wr
        unsigned sw[8];
        f16x8 av[8];
        #pragma unroll
        for (int tt = 0; tt < 8; ++tt) {
            sw[tt] = b0 ^ ((tt & 1) ? P.Mt[0] : 0)
                        ^ ((tt & 2) ? P.Mt[1] : 0)
                        ^ ((tt & 4) ? P.Mt[2] : 0);
            av[tt] = *(const f16x8*)(Sh + plane_off + (sw[tt] ^ (q01 << 3)));
        }
        #pragma unroll
        for (int tt = 0; tt < 8; ++tt) {
            const f32x4 d1 = __builtin_amdgcn_mfma_f32_16x16x32_f16(av[tt], bf1, z4, 0, 0, 0);
            const f32x4 d2 = __builtin_amdgcn_mfma_f32_16x16x32_f16(av[tt], bf2, z4, 0, 0, 0);
            union { fp16x2 h2[2]; unsigned long long u; } c1, c2;
            c1.h2[0] = __builtin_amdgcn_cvt_pkrtz(d1[0], d1[1]);
            c1.h2[1] = __builtin_amdgcn_cvt_pkrtz(d1[2], d1[3]);
            c2.h2[0] = __builtin_amdgcn_cvt_pkrtz(d2[0], d2[1]);
            c2.h2[1] = __builtin_amdgcn_cvt_pkrtz(d2[2], d2[3]);
            const unsigned wu = sw[tt] ^ ((unsigned)q << 2);
            const unsigned lds_addr = (unsigned)(uintptr_t)(Sh + wu);
            // Re plane at +0, Im plane at +64*512B = +32768B = +NST f16
            asm volatile("ds_write2st64_b64 %0, %1, %2 offset0:0 offset1:64"
                         :: "v"(lds_addr), "v"(c1.u), "v"(c2.u) : "memory");
        }
        __syncthreads();
    }

    // ---- <Z_0>: interleaved, conflict-free reads (wave reads 1 KiB contiguous) ----
    float acc = 0.f;
    {
        #pragma unroll
        for (int cch = 0; cch < 4; ++cch) {
            const unsigned addr = (unsigned)cch * 4096u + (unsigned)tid * 8u;
            const f16x8 rr = *(const f16x8*)(Sh + addr);
            const f16x8 ii = *(const f16x8*)(Sh + NST + addr);
            const int pb = __popc(addr & (unsigned)pl.measR) & 1;
            #pragma unroll
            for (int e = 0; e < 8; ++e) {
                const float re = (float)rr[e], im = (float)ii[e];
                const float pw = fmaf(re, re, im * im);
                const int sgn = pb ^ (__popc((unsigned)e & (unsigned)pl.measR) & 1);
                acc += sgn ? -pw : pw;
            }
        }
    }
    #pragma unroll
    for (int off = 32; off > 0; off >>= 1) acc += __shfl_down(acc, off);
    if ((tid & 63) == 0) red[wv] = acc;
    __syncthreads();
    if (tid == 0) {
        float s = 0.f;
        #pragma unroll
        for (int i = 0; i < THREADS / 64; ++i) s += red[i];
        out[b] = s;
    }
}

// ---------------- host-side GF(2) layout scheduling ----------------
struct GFm { u16 col[14]; };   // col[b] = image of e_b

static unsigned ringp_host(unsigned x) {
    unsigned s = x;
    s ^= s >> 1; s ^= s >> 2; s ^= s >> 4; s ^= s >> 8;
    s &= 0x3FFFu;
    return (s ^ ((s & 1u) << 13)) & 0x3FFFu;
}
static u16 gf_apply(const GFm& m, u16 v) {
    u16 r = 0;
    for (int b = 0; b < 14; ++b) if ((v >> b) & 1) r ^= m.col[b];
    return r;
}
static GFm gf_compose(const GFm& A, const GFm& B) {
    GFm C;
    for (int b = 0; b < 14; ++b) C.col[b] = gf_apply(A, B.col[b]);
    return C;
}
static void rows_from(const GFm& A, u16 r[14]) {
    for (int i = 0; i < 14; ++i) {
        u16 mm = 0;
        for (int b = 0; b < 14; ++b) mm |= (u16)(((A.col[b] >> i) & 1) << b);
        r[i] = mm;
    }
}
static GFm from_rows(const u16 r[14]) {
    GFm A;
    for (int b = 0; b < 14; ++b) {
        u16 c = 0;
        for (int i = 0; i < 14; ++i) c |= (u16)(((r[i] >> b) & 1) << i);
        A.col[b] = c;
    }
    return A;
}
static GFm gf_inv(const GFm& A) {
    u16 M[14], I[14];
    rows_from(A, M);
    for (int i = 0; i < 14; ++i) I[i] = (u16)(1u << i);
    for (int c = 0; c < 14; ++c) {
        int p = c;
        while (p < 14 && !((M[p] >> c) & 1)) ++p;
        if (p == 14) continue;
        u16 t = M[c]; M[c] = M[p]; M[p] = t;
        t = I[c]; I[c] = I[p]; I[p] = t;
        for (int r2 = 0; r2 < 14; ++r2)
            if (r2 != c && ((M[r2] >> c) & 1)) { M[r2] ^= M[c]; I[r2] ^= I[c]; }
    }
    return from_rows(I);
}

static void build_plan(Plan& pl) {
    GFm ring, ringInv;
    for (int b = 0; b < 14; ++b) ring.col[b] = (u16)ringp_host(1u << b);
    ringInv = gf_inv(ring);

    GFm phi;
    for (int j = 0; j < 4; ++j) phi.col[10 + j] = (u16)(1u << j);
    for (int j = 0; j < 4; ++j) phi.col[6 + j]  = (u16)(1u << (4 + j));
    for (int j = 0; j < 4; ++j) phi.col[2 + j]  = (u16)(1u << (8 + j));
    phi.col[0] = (u16)(1u << 12);
    phi.col[1] = (u16)(1u << 13);

    for (int b = 0; b < 14; ++b) pl.initM[b] = gf_apply(phi, ring.col[b]);

    const int gb[4][4] = {{10,11,12,13},{6,7,8,9},{2,3,4,5},{0,1,6,7}};

    for (int p = 0; p < NPASS; ++p) {
        const int g = p & 3;
        u16 uv[4];
        if (g < 3) for (int j = 0; j < 4; ++j) uv[j] = (u16)(1u << gb[g + 1][j]);
        else       for (int j = 0; j < 4; ++j) uv[j] = ringInv.col[10 + j];
        for (int j = 0; j < 4; ++j) pl.ps[p].Mm[j] = gf_apply(phi, uv[j]);

        u16 span[14]; int ns = 0;
        u16 tv[6]; int nt = 0;
        auto tryAdd = [&](u16 v) -> bool {
            bool ch = true;
            while (ch) {
                ch = false;
                for (int i = 0; i < ns; ++i) {
                    const int tb = 31 - __builtin_clz((unsigned)span[i]);
                    if ((v >> tb) & 1) { v ^= span[i]; ch = true; }
                }
            }
            if (!v) return false;
            span[ns++] = v;
            return true;
        };
        for (int j = 0; j < 4; ++j) tryAdd((u16)(1u << gb[g][j]));
        for (int j = 0; j < 4; ++j) tryAdd(uv[j]);
        for (int b2 = 0; b2 < 14 && nt < 6; ++b2)
            if (tryAdd((u16)(1u << b2))) tv[nt++] = (u16)(1u << b2);
        for (int i = 0; i < 3; ++i) pl.ps[p].Mt[i] = gf_apply(phi, tv[i]);      // tile
        for (int i = 0; i < 3; ++i) pl.ps[p].Mw[i] = gf_apply(phi, tv[i + 3]);  // wave

        GFm Bm;
        for (int j = 0; j < 4; ++j) Bm.col[j]     = (u16)(1u << gb[g][j]);
        for (int j = 0; j < 4; ++j) Bm.col[4 + j] = uv[j];
        for (int i = 0; i < 6; ++i) Bm.col[8 + i] = tv[i];
        GFm Binv = gf_inv(Bm);
        u16 img[14];
        for (int j = 0; j < 4; ++j) img[j]     = pl.ps[p].Mm[j];
        for (int j = 0; j < 4; ++j) img[4 + j] = (u16)(1u << j);
        for (int i = 0; i < 6; ++i) img[8 + i] = gf_apply(phi, tv[i]);
        GFm nphi;
        for (int b2 = 0; b2 < 14; ++b2) {
            const u16 coef = gf_apply(Binv, (u16)(1u << b2));
            u16 v = 0;
            for (int j = 0; j < 14; ++j) if ((coef >> j) & 1) v ^= img[j];
            nphi.col[b2] = v;
        }
        if (g == 3) nphi = gf_compose(nphi, ringInv);
        phi = nphi;
    }

    GFm pinv = gf_inv(phi);
    u16 rows[14];
    rows_from(pinv, rows);
    pl.measR = rows[13];
    pl._pad = 0;
}

// ---- bank-spread map A: out[3:5] = M*s[3:5] ^ L*s[6:13], identity elsewhere.
// Constraints: M invertible, M*e3 = e3 (preserves init-chunk identity + alignment).
struct SwzP { unsigned c4, c5; unsigned char Lc[8]; };

static unsigned proj35(const SwzP& s, u16 v) {
    unsigned a = ((unsigned)v >> 3) & 7u;
    unsigned r = (a & 1u) ? 1u : 0u;          // col for input bit3 = e3
    if (a & 2u) r ^= s.c4;
    if (a & 4u) r ^= s.c5;
    unsigned hb = ((unsigned)v >> 6) & 0xFFu;
    for (int c = 0; c < 8; ++c) if ((hb >> c) & 1u) r ^= s.Lc[c];
    return r & 7u;
}
static int rank3(const unsigned* q, int n) {
    unsigned bas[3] = {0, 0, 0};
    int r = 0;
    for (int j = 0; j < n; ++j) {
        unsigned v = q[j];
        for (int bit = 2; bit >= 0; --bit) {
            if (!((v >> bit) & 1u)) continue;
            if (bas[bit]) { v ^= bas[bit]; continue; }
            bas[bit] = v; ++r; v = 0; break;
        }
    }
    return r;
}
static bool minv_ok(unsigned c4, unsigned c5) {  // {e0, c4, c5} rank 3
    const unsigned q[3] = {1u, c4 & 7u, c5 & 7u};
    return rank3(q, 3) == 3;
}
static int score_swz(const SwzP& s, const u16 MmRaw[NPASS][4]) {
    int bad = 0;
    for (int p = 0; p < NPASS; ++p) {
        unsigned q[4];
        for (int j = 0; j < 4; ++j) q[j] = proj35(s, MmRaw[p][j]);
        bad += 3 - rank3(q, 4);
    }
    return bad;
}
static GFm A_from(const SwzP& s) {
    GFm A;
    for (int b = 0; b < 14; ++b) A.col[b] = (u16)(1u << b);
    A.col[4] = (u16)((s.c4 & 7u) << 3);
    A.col[5] = (u16)((s.c5 & 7u) << 3);
    for (int c = 0; c < 8; ++c)
        A.col[6 + c] = (u16)((1u << (6 + c)) ^ (((unsigned)s.Lc[c] & 7u) << 3));
    return A;
}
static void choose_swz(const Plan& raw, GFm& A, GFm& Ainv) {
    u16 MmRaw[NPASS][4];
    for (int p = 0; p < NPASS; ++p)
        for (int j = 0; j < 4; ++j) MmRaw[p][j] = raw.ps[p].Mm[j];

    // candidate 0 = the long-standing fixed hash (baseline)
    SwzP best = {2u, 4u, {1, 2, 4, 1, 2, 5, 2, 4}};
    int bestScore = score_swz(best, MmRaw);

    uint64_t rng = 0x9E3779B97F4A7C15ull;
    auto rnd = [&]() -> unsigned {
        rng = rng * 6364136223846793005ull + 1442695040888963407ull;
        return (unsigned)(rng >> 33);
    };
    for (int t = 0; t < 8000 && bestScore > 0; ++t) {
        SwzP s;
        s.c4 = rnd() & 7u; s.c5 = rnd() & 7u;
        if (!minv_ok(s.c4, s.c5)) continue;
        for (int c = 0; c < 8; ++c) s.Lc[c] = (unsigned char)(rnd() & 7u);
        const int sc = score_swz(s, MmRaw);
        if (sc < bestScore) { bestScore = sc; best = s; }
    }
    A = A_from(best);
    Ainv = gf_inv(A);
}
static void fold_A(Plan& pl, const GFm& A, const GFm& Ainv) {
    for (int p = 0; p < NPASS; ++p) {
        for (int j = 0; j < 4; ++j) pl.ps[p].Mm[j] = gf_apply(A, pl.ps[p].Mm[j]);
        for (int j = 0; j < 3; ++j) pl.ps[p].Mt[j] = gf_apply(A, pl.ps[p].Mt[j]);
        for (int j = 0; j < 3; ++j) pl.ps[p].Mw[j] = gf_apply(A, pl.ps[p].Mw[j]);
    }
    for (int b = 0; b < 14; ++b) pl.initM[b] = gf_apply(A, pl.initM[b]);
    // sign(storage s) = parity(r . logical), logical = Ainv(s)
    //   => measR'_b = parity(r & Ainv.col[b])
    const unsigned r = pl.measR;
    u16 nr = 0;
    for (int b = 0; b < 14; ++b)
        if (__builtin_popcount(r & (unsigned)Ainv.col[b]) & 1) nr |= (u16)(1u << b);
    pl.measR = nr;
}

extern "C" void kernel_launch(void* const* d_in, const int* in_sizes, int n_in,
                              void* d_out, int out_size, void* d_ws, size_t ws_size,
                              hipStream_t stream) {
    const float* x_raw  = (const float*)d_in[0];
    const float* angles = (const float*)d_in[1];
    float* out = (float*)d_out;
    const int bsz = in_sizes[0] / NW;

    Plan pl;
    build_plan(pl);
    GFm A, Ainv;
    choose_swz(pl, A, Ainv);
    fold_A(pl, A, Ainv);

    // d_ws layout: [0,24576) dual W tables (f16, per q-half), then layer-0 gates
    f16*    wt_g = (f16*)d_ws;
    float2* u0_g = (float2*)((char*)d_ws + (size_t)2 * NPASS * WTP * sizeof(f16));

    vqc_pre<<<dim3(1), dim3(PRETHR), 0, stream>>>(angles, wt_g, u0_g);

    // LDS: 64K state + 224B G0c + 32B red = 65792 B -> 2 blocks/CU
    const size_t lds = (size_t)2 * NST * sizeof(f16)
                     + (size_t)(2 * NW) * sizeof(float2)
                     + (size_t)(THREADS / 64) * sizeof(float);
    (void)hipFuncSetAttribute((const void*)vqc_kernel,
                              hipFuncAttributeMaxDynamicSharedMemorySize, (int)lds);
    vqc_kernel<<<dim3(bsz), dim3(THREADS), lds, stream>>>(x_raw, wt_g, u0_g, out, pl);
}

// Round 11
// 100.925 us; speedup vs baseline: 1.1828x; 1.0561x over previous
//
#include <hip/hip_runtime.h>
#include <cmath>
#include <cstdint>

#define NW       14
#define NST      (1 << NW)      // 16384 amplitudes
#define THREADS  512
#define PRETHR   768
#define NPASS    12             // layers 1..3 x 4 groups
#define WTP      512            // per-pass W table: TR[256] + TI[256] f16

typedef _Float16 f16;
typedef __fp16   fp16x2 __attribute__((ext_vector_type(2)));
typedef _Float16 f16x8 __attribute__((ext_vector_type(8)));
typedef float    f32x4 __attribute__((ext_vector_type(4)));
typedef unsigned short u16;

// Per-pass XOR-mask addressing: storage = A(phi_p(x)); the bank-spread map A
// (GF(2)-linear, identity on bits 0..2, fixes e3) is folded into all masks
// HOST-side. State layout: PLANAR (Re [0,16K), Im [16K,32K) f16).
// W tables in GLOBAL (L1/L2-resident), duplicated per q-half with signs
// PRE-FOLDED: qh=0 -> [TR, TI], qh=1 -> [-TI, TR].
// LAST PASS FUSED WITH MEASUREMENT: |amp|^2 taken from the f32 MFMA
// accumulators directly (no final pack/LDS-write/barrier/re-read).
struct PassArg { u16 Mm[4]; u16 Mt[3]; u16 Mw[3]; };
struct Plan { PassArg ps[NPASS]; u16 initM[14]; u16 measR; u16 _pad; };

__device__ __forceinline__ float2 cmulf(float2 a, float2 b) {
    return make_float2(a.x * b.x - a.y * b.y, a.x * b.y + a.y * b.x);
}
// W-table in-block offset with quad-spread (keeps 8-f16 alignment)
__device__ __host__ __forceinline__ unsigned wtofs(unsigned m, unsigned q01) {
    return (m * 16 + q01 * 8) ^ (((m >> 2) & 1u) << 3);
}

// ---------------- pre-kernel: shared tables (angles only) -> d_ws ----------------
__global__ __launch_bounds__(PRETHR)
void vqc_pre(const float* __restrict__ angles, f16* __restrict__ wt_g,
             float2* __restrict__ u0_g)
{
    __shared__ float2 G[4 * NW * 4];
    const int tid = threadIdx.x;

    if (tid < 4 * NW) {
        const int k = tid / NW, w = tid % NW;
        const float a  = angles[(k * NW + w) * 3 + 0];
        const float bb = angles[(k * NW + w) * 3 + 1];
        const float c  = angles[(k * NW + w) * 3 + 2];
        float sa, ca, sb, cb, sc, cc;
        sincosf(a * 0.5f, &sa, &ca);
        sincosf(bb * 0.5f, &sb, &cb);
        sincosf(c * 0.5f, &sc, &cc);
        float2 m00 = make_float2(cb * ca,  sb * sa);
        float2 m01 = make_float2(-sb * ca, -cb * sa);
        float2 m10 = make_float2(sb * ca,  -cb * sa);
        float2 m11 = make_float2(cb * ca,  -sb * sa);
        const float2 e0 = make_float2(cc, -sc), e1 = make_float2(cc, sc);
        const float2 u00 = cmulf(e0, m00), u01 = cmulf(e0, m01);
        const float2 u10 = cmulf(e1, m10), u11 = cmulf(e1, m11);
        const int gi = (k * NW + w) * 4;
        G[gi + 0] = u00; G[gi + 1] = u01; G[gi + 2] = u10; G[gi + 3] = u11;
        if (k == 0) {   // layer-0 STATIC gate (per-sample RY_enc folded in main kernel)
            u0_g[w * 4 + 0] = u00; u0_g[w * 4 + 1] = u01;
            u0_g[w * 4 + 2] = u10; u0_g[w * 4 + 3] = u11;
        }
    }
    __syncthreads();

    // W tables: TR[a'][a] = Re W[a'][a], TI = Im (16x16 per pass), layers 1..3
    {
        const int p = tid >> 6, l6 = tid & 63;
        const int ap = l6 & 15, ahalf = (l6 >> 4) & 1, dup = l6 >> 5;
        const int layer = (p >> 2) + 1, g = p & 3;

        float2 p3;
        if (g == 3) {
            p3 = make_float2((((ap >> 3) & 1) == ahalf) ? 1.f : 0.f, 0.f);
        } else {
            const int wire = 13 - (10 - 4 * g + 3);
            p3 = G[(layer * NW + wire) * 4 + ((ap >> 3) & 1) * 2 + ahalf];
        }
        float2 e0a, e0b, e1a, e1b, e2a, e2b;
        {
            const int r0 = ap & 1, r1 = (ap >> 1) & 1, r2 = (ap >> 2) & 1;
            if (g == 3) {
                const float2* G13 = G + (layer * NW + 13) * 4;
                const float2* G12 = G + (layer * NW + 12) * 4;
                e0a = G13[r0 * 2 + 0]; e0b = G13[r0 * 2 + 1];
                e1a = G12[r1 * 2 + 0]; e1b = G12[r1 * 2 + 1];
                e2a = make_float2(r2 == 0 ? 1.f : 0.f, 0.f);
                e2b = make_float2(r2 == 1 ? 1.f : 0.f, 0.f);
            } else {
                const float2* G0 = G + (layer * NW + (13 - (10 - 4 * g + 0))) * 4;
                const float2* G1 = G + (layer * NW + (13 - (10 - 4 * g + 1))) * 4;
                const float2* G2 = G + (layer * NW + (13 - (10 - 4 * g + 2))) * 4;
                e0a = G0[r0 * 2 + 0]; e0b = G0[r0 * 2 + 1];
                e1a = G1[r1 * 2 + 0]; e1b = G1[r1 * 2 + 1];
                e2a = G2[r2 * 2 + 0]; e2b = G2[r2 * 2 + 1];
            }
        }
        f16x8 frag;
        #pragma unroll
        for (int j2 = 0; j2 < 8; ++j2) {
            float2 v = cmulf(p3, (j2 & 4) ? e2b : e2a);
            v = cmulf(v, (j2 & 2) ? e1b : e1a);
            v = cmulf(v, (j2 & 1) ? e0b : e0a);
            frag[j2] = (f16)(dup ? v.y : v.x);
        }
        const unsigned ofs = wtofs(ap, ahalf);
        // q-half 0: [TR | TI]  (dup=0 -> slot A, dup=1 -> slot B)
        *(f16x8*)(wt_g + p * WTP + dup * 256 + ofs) = frag;
        // q-half 1: [-TI | TR] (dup=1 -> slot A negated, dup=0 -> slot B)
        const f16x8 nfrag = dup ? -frag : frag;
        *(f16x8*)(wt_g + NPASS * WTP + p * WTP + (dup ? 0 : 256) + ofs) = nfrag;
    }
}

// ---------------- main kernel: per-sample ----------------
__global__ __launch_bounds__(THREADS, 4)
void vqc_kernel(const float* __restrict__ x_raw, const f16* __restrict__ wt_g,
                const float2* __restrict__ u0_g, float* __restrict__ out, Plan pl)
{
    extern __shared__ char smem[];
    f16*    Sh  = (f16*)smem;                    // Re [0,16K), Im [16K,32K) f16 (64 KB)
    float2* G0c = (float2*)(Sh + 2 * NST);       // 14 x {col0_row0, col0_row1}
    float*  red = (float*)(G0c + 2 * NW);

    const int b   = blockIdx.x;
    const int tid = threadIdx.x;
    const int lane = tid & 63, wv = tid >> 6;
    const int q = lane >> 4, m = lane & 15;

    // ---- per-sample layer-0 encode: col0 of U_static * RY_enc(x_w) ----
    if (tid < NW) {
        const float xe = tanhf(x_raw[b * NW + tid]) * 3.14159265358979f;
        float se, ce;
        sincosf(xe * 0.5f, &se, &ce);
        const float2 u00 = u0_g[tid * 4 + 0], u01 = u0_g[tid * 4 + 1];
        const float2 u10 = u0_g[tid * 4 + 2], u11 = u0_g[tid * 4 + 3];
        G0c[tid * 2 + 0] = make_float2(u00.x * ce + u01.x * se, u00.y * ce + u01.y * se);
        G0c[tid * 2 + 1] = make_float2(u10.x * ce + u11.x * se, u10.y * ce + u11.y * se);
    }
    __syncthreads();

    // ---- init: product state after all layer-0 1q gates ----
    // Key identity (A fixes e0..e3, identity on bits 0..2):
    //   initM[9]^initM[10]=1, [10]^[11]=2, [11]^[12]=4, [12]^[13]=8.
    // Each thread's 32 amps land in exactly TWO aligned 16-elem chunks.
    {
        float2 common = make_float2(1.f, 0.f);
        #pragma unroll
        for (int bit = 0; bit < 9; ++bit) {          // x bits 0..8 from tid (wires 13..5)
            const int w = 13 - bit;
            const float2 f = ((tid >> bit) & 1) ? G0c[w * 2 + 1] : G0c[w * 2 + 0];
            common = cmulf(common, f);
        }
        unsigned p9 = 0;
        #pragma unroll
        for (int bit = 0; bit < 9; ++bit)
            p9 ^= ((tid >> bit) & 1) ? (unsigned)pl.initM[bit] : 0u;

        const float2 f0a = G0c[4*2+0], f0b = G0c[4*2+1];   // j bit0 -> wire 4
        const float2 f1a = G0c[3*2+0], f1b = G0c[3*2+1];
        const float2 f2a = G0c[2*2+0], f2b = G0c[2*2+1];
        const float2 f3a = G0c[1*2+0], f3b = G0c[1*2+1];
        const float2 f4a = G0c[0*2+0], f4b = G0c[0*2+1];   // j bit4 -> wire 0

        const unsigned S   = (unsigned)pl.initM[13];
        const unsigned Slo = S & 15u, Hh = S & ~15u;
        const unsigned plo = p9 & 15u, B0 = p9 & ~15u;

        #pragma unroll
        for (int c = 0; c < 2; ++c) {
            const unsigned r = plo ^ (c ? Slo : 0u);
            const bool s0 = ((r       ) & 1u) != 0;                    // o0 ^ r0
            const bool s1 = (((r) ^ (r >> 1)) & 1u) != 0;              // (o0^o1) ^ (r0^r1)
            const bool s2 = (((r >> 1) ^ (r >> 2)) & 1u) != 0;
            const bool s3 = (((r >> 2) ^ (r >> 3)) & 1u) != 0;
            const bool s4 = ((((r >> 3) & 1u) ^ (unsigned)c) != 0);    // o3 ^ (r3^c)
            const float2 F0[2] = { s0 ? f0b : f0a, s0 ? f0a : f0b };
            const float2 F1[2] = { s1 ? f1b : f1a, s1 ? f1a : f1b };
            const float2 F2[2] = { s2 ? f2b : f2a, s2 ? f2a : f2b };
            const float2 F3[2] = { s3 ? f3b : f3a, s3 ? f3a : f3b };
            const float2 F4[2] = { s4 ? f4b : f4a, s4 ? f4a : f4b };
            // amp(c,o) = common * F4[o3] * F3[o2^o3] * F2[o1^o2] * F1[o0^o1] * F0[o0]
            const float2 A0 = cmulf(common, F4[0]);
            const float2 A1 = cmulf(common, F4[1]);
            float2 Bt[4];                         // [o3*2+o2] = A[o3]*F3[o2^o3]
            Bt[0] = cmulf(A0, F3[0]); Bt[1] = cmulf(A0, F3[1]);
            Bt[2] = cmulf(A1, F3[1]); Bt[3] = cmulf(A1, F3[0]);
            float2 Ct[8];                         // [(o3o2)*2+o1] = Bt*F2[o1^o2]
            #pragma unroll
            for (int o32 = 0; o32 < 4; ++o32) {
                const int o2 = o32 & 1;
                Ct[o32 * 2 + 0] = cmulf(Bt[o32], F2[o2]);
                Ct[o32 * 2 + 1] = cmulf(Bt[o32], F2[1 ^ o2]);
            }
            float2 Gt[4];                         // [o1*2+o0] = F1[o0^o1]*F0[o0]
            Gt[0] = cmulf(F1[0], F0[0]); Gt[1] = cmulf(F1[1], F0[1]);
            Gt[2] = cmulf(F1[1], F0[0]); Gt[3] = cmulf(F1[0], F0[1]);

            union { f16 h[8]; f16x8 v; } hR[2], hI[2];
            #pragma unroll
            for (int o = 0; o < 16; ++o) {
                const int o0 = o & 1, o1 = (o >> 1) & 1;
                const float2 amp = cmulf(Ct[o >> 1], Gt[o1 * 2 + o0]);
                hR[o >> 3].h[o & 7] = (f16)amp.x;
                hI[o >> 3].h[o & 7] = (f16)amp.y;
            }
            const unsigned bb = B0 ^ (c ? Hh : 0u);   // 16-elem (32 B) aligned
            *(f16x8*)(Sh + bb)           = hR[0].v;
            *(f16x8*)(Sh + bb + 8)       = hR[1].v;
            *(f16x8*)(Sh + NST + bb)     = hI[0].v;
            *(f16x8*)(Sh + NST + bb + 8) = hI[1].v;
        }
    }
    __syncthreads();

    // ---- 12 MFMA passes, in-place, ONE barrier per pass; LAST PASS FUSED ----
    // A wave's read and write sets are the SAME wave-private coset
    //   wb ^ span{1,2,4,8, Mm[0..3], Mt[0..2]}  (Mw cosets disjoint),
    // and per-wave DS ops execute in order -> no mid-pass barrier needed.
    // (bf1,bf2) from the per-q-half pre-negated GLOBAL W table (VMEM pipe).
    // Passes 0..10: Re/Im writes fused via ds_write2st64_b64 offset1:64.
    // Pass 11: measurement taken DIRECTLY from the f32 MFMA accumulators --
    //   output positions wu..wu+3 (wu = sw ^ q<<2, wu==0 mod 4), sign =
    //   parity(wu & measR) ^ parity(r & measR). No pack/write/barrier/re-read.
    const unsigned plane_off = (unsigned)(q >> 1) << 14;
    const unsigned q01 = (unsigned)(q & 1);
    const f16* wbase = wt_g + (unsigned)(q >> 1) * (NPASS * WTP)
                            + wtofs((unsigned)m, q01);
    const f32x4 z4 = {0.f, 0.f, 0.f, 0.f};
    const unsigned mr = (unsigned)pl.measR;
    int srt[4];
    #pragma unroll
    for (int r = 0; r < 4; ++r) srt[r] = __popc((unsigned)r & mr) & 1;
    float acc = 0.f;

    #pragma unroll
    for (int p = 0; p < NPASS; ++p) {
        const PassArg& P = pl.ps[p];
        const unsigned pm = ((m & 1) ? P.Mm[0] : 0) ^ ((m & 2) ? P.Mm[1] : 0)
                          ^ ((m & 4) ? P.Mm[2] : 0) ^ ((m & 8) ? P.Mm[3] : 0);
        const unsigned wb = ((wv & 1) ? P.Mw[0] : 0) ^ ((wv & 2) ? P.Mw[1] : 0)
                          ^ ((wv & 4) ? P.Mw[2] : 0);
        const unsigned b0 = pm ^ wb;
        const f16x8 bf1 = *(const f16x8*)(wbase + p * WTP);         // q<2: Wr ; q>=2: -Wi
        const f16x8 bf2 = *(const f16x8*)(wbase + p * WTP + 256);   // q<2: Wi ; q>=2:  Wr
        unsigned sw[8];
        f16x8 av[8];
        #pragma unroll
        for (int tt = 0; tt < 8; ++tt) {
            sw[tt] = b0 ^ ((tt & 1) ? P.Mt[0] : 0)
                        ^ ((tt & 2) ? P.Mt[1] : 0)
                        ^ ((tt & 4) ? P.Mt[2] : 0);
            av[tt] = *(const f16x8*)(Sh + plane_off + (sw[tt] ^ (q01 << 3)));
        }
        if (p < NPASS - 1) {
            #pragma unroll
            for (int tt = 0; tt < 8; ++tt) {
                const f32x4 d1 = __builtin_amdgcn_mfma_f32_16x16x32_f16(av[tt], bf1, z4, 0, 0, 0);
                const f32x4 d2 = __builtin_amdgcn_mfma_f32_16x16x32_f16(av[tt], bf2, z4, 0, 0, 0);
                union { fp16x2 h2[2]; unsigned long long u; } c1, c2;
                c1.h2[0] = __builtin_amdgcn_cvt_pkrtz(d1[0], d1[1]);
                c1.h2[1] = __builtin_amdgcn_cvt_pkrtz(d1[2], d1[3]);
                c2.h2[0] = __builtin_amdgcn_cvt_pkrtz(d2[0], d2[1]);
                c2.h2[1] = __builtin_amdgcn_cvt_pkrtz(d2[2], d2[3]);
                const unsigned wu = sw[tt] ^ ((unsigned)q << 2);
                const unsigned lds_addr = (unsigned)(uintptr_t)(Sh + wu);
                // Re plane at +0, Im plane at +64*512B = +32768B = +NST f16
                asm volatile("ds_write2st64_b64 %0, %1, %2 offset0:0 offset1:64"
                             :: "v"(lds_addr), "v"(c1.u), "v"(c2.u) : "memory");
            }
            __syncthreads();
        } else {
            #pragma unroll
            for (int tt = 0; tt < 8; ++tt) {
                const f32x4 d1 = __builtin_amdgcn_mfma_f32_16x16x32_f16(av[tt], bf1, z4, 0, 0, 0);
                const f32x4 d2 = __builtin_amdgcn_mfma_f32_16x16x32_f16(av[tt], bf2, z4, 0, 0, 0);
                const unsigned wu = sw[tt] ^ ((unsigned)q << 2);
                const int pb = __popc(wu & mr) & 1;
                #pragma unroll
                for (int r = 0; r < 4; ++r) {
                    const float pw = fmaf(d1[r], d1[r], d2[r] * d2[r]);
                    acc += (pb ^ srt[r]) ? -pw : pw;
                }
            }
        }
    }

    // ---- block reduction of <Z_0> ----
    #pragma unroll
    for (int off = 32; off > 0; off >>= 1) acc += __shfl_down(acc, off);
    if ((tid & 63) == 0) red[wv] = acc;
    __syncthreads();
    if (tid == 0) {
        float s = 0.f;
        #pragma unroll
        for (int i = 0; i < THREADS / 64; ++i) s += red[i];
        out[b] = s;
    }
}

// ---------------- host-side GF(2) layout scheduling ----------------
struct GFm { u16 col[14]; };   // col[b] = image of e_b

static unsigned ringp_host(unsigned x) {
    unsigned s = x;
    s ^= s >> 1; s ^= s >> 2; s ^= s >> 4; s ^= s >> 8;
    s &= 0x3FFFu;
    return (s ^ ((s & 1u) << 13)) & 0x3FFFu;
}
static u16 gf_apply(const GFm& m, u16 v) {
    u16 r = 0;
    for (int b = 0; b < 14; ++b) if ((v >> b) & 1) r ^= m.col[b];
    return r;
}
static GFm gf_compose(const GFm& A, const GFm& B) {
    GFm C;
    for (int b = 0; b < 14; ++b) C.col[b] = gf_apply(A, B.col[b]);
    return C;
}
static void rows_from(const GFm& A, u16 r[14]) {
    for (int i = 0; i < 14; ++i) {
        u16 mm = 0;
        for (int b = 0; b < 14; ++b) mm |= (u16)(((A.col[b] >> i) & 1) << b);
        r[i] = mm;
    }
}
static GFm from_rows(const u16 r[14]) {
    GFm A;
    for (int b = 0; b < 14; ++b) {
        u16 c = 0;
        for (int i = 0; i < 14; ++i) c |= (u16)(((r[i] >> b) & 1) << i);
        A.col[b] = c;
    }
    return A;
}
static GFm gf_inv(const GFm& A) {
    u16 M[14], I[14];
    rows_from(A, M);
    for (int i = 0; i < 14; ++i) I[i] = (u16)(1u << i);
    for (int c = 0; c < 14; ++c) {
        int p = c;
        while (p < 14 && !((M[p] >> c) & 1)) ++p;
        if (p == 14) continue;
        u16 t = M[c]; M[c] = M[p]; M[p] = t;
        t = I[c]; I[c] = I[p]; I[p] = t;
        for (int r2 = 0; r2 < 14; ++r2)
            if (r2 != c && ((M[r2] >> c) & 1)) { M[r2] ^= M[c]; I[r2] ^= I[c]; }
    }
    return from_rows(I);
}

static void build_plan(Plan& pl) {
    GFm ring, ringInv;
    for (int b = 0; b < 14; ++b) ring.col[b] = (u16)ringp_host(1u << b);
    ringInv = gf_inv(ring);

    GFm phi;
    for (int j = 0; j < 4; ++j) phi.col[10 + j] = (u16)(1u << j);
    for (int j = 0; j < 4; ++j) phi.col[6 + j]  = (u16)(1u << (4 + j));
    for (int j = 0; j < 4; ++j) phi.col[2 + j]  = (u16)(1u << (8 + j));
    phi.col[0] = (u16)(1u << 12);
    phi.col[1] = (u16)(1u << 13);

    for (int b = 0; b < 14; ++b) pl.initM[b] = gf_apply(phi, ring.col[b]);

    const int gb[4][4] = {{10,11,12,13},{6,7,8,9},{2,3,4,5},{0,1,6,7}};

    for (int p = 0; p < NPASS; ++p) {
        const int g = p & 3;
        u16 uv[4];
        if (g < 3) for (int j = 0; j < 4; ++j) uv[j] = (u16)(1u << gb[g + 1][j]);
        else       for (int j = 0; j < 4; ++j) uv[j] = ringInv.col[10 + j];
        for (int j = 0; j < 4; ++j) pl.ps[p].Mm[j] = gf_apply(phi, uv[j]);

        u16 span[14]; int ns = 0;
        u16 tv[6]; int nt = 0;
        auto tryAdd = [&](u16 v) -> bool {
            bool ch = true;
            while (ch) {
                ch = false;
                for (int i = 0; i < ns; ++i) {
                    const int tb = 31 - __builtin_clz((unsigned)span[i]);
                    if ((v >> tb) & 1) { v ^= span[i]; ch = true; }
                }
            }
            if (!v) return false;
            span[ns++] = v;
            return true;
        };
        for (int j = 0; j < 4; ++j) tryAdd((u16)(1u << gb[g][j]));
        for (int j = 0; j < 4; ++j) tryAdd(uv[j]);
        for (int b2 = 0; b2 < 14 && nt < 6; ++b2)
            if (tryAdd((u16)(1u << b2))) tv[nt++] = (u16)(1u << b2);
        for (int i = 0; i < 3; ++i) pl.ps[p].Mt[i] = gf_apply(phi, tv[i]);      // tile
        for (int i = 0; i < 3; ++i) pl.ps[p].Mw[i] = gf_apply(phi, tv[i + 3]);  // wave

        GFm Bm;
        for (int j = 0; j < 4; ++j) Bm.col[j]     = (u16)(1u << gb[g][j]);
        for (int j = 0; j < 4; ++j) Bm.col[4 + j] = uv[j];
        for (int i = 0; i < 6; ++i) Bm.col[8 + i] = tv[i];
        GFm Binv = gf_inv(Bm);
        u16 img[14];
        for (int j = 0; j < 4; ++j) img[j]     = pl.ps[p].Mm[j];
        for (int j = 0; j < 4; ++j) img[4 + j] = (u16)(1u << j);
        for (int i = 0; i < 6; ++i) img[8 + i] = gf_apply(phi, tv[i]);
        GFm nphi;
        for (int b2 = 0; b2 < 14; ++b2) {
            const u16 coef = gf_apply(Binv, (u16)(1u << b2));
            u16 v = 0;
            for (int j = 0; j < 14; ++j) if ((coef >> j) & 1) v ^= img[j];
            nphi.col[b2] = v;
        }
        if (g == 3) nphi = gf_compose(nphi, ringInv);
        phi = nphi;
    }

    GFm pinv = gf_inv(phi);
    u16 rows[14];
    rows_from(pinv, rows);
    pl.measR = rows[13];
    pl._pad = 0;
}

// ---- bank-spread map A: out[3:5] = M*s[3:5] ^ L*s[6:13], identity elsewhere.
// Constraints: M invertible, M*e3 = e3 (preserves init-chunk identity + alignment).
struct SwzP { unsigned c4, c5; unsigned char Lc[8]; };

static unsigned proj35(const SwzP& s, u16 v) {
    unsigned a = ((unsigned)v >> 3) & 7u;
    unsigned r = (a & 1u) ? 1u : 0u;          // col for input bit3 = e3
    if (a & 2u) r ^= s.c4;
    if (a & 4u) r ^= s.c5;
    unsigned hb = ((unsigned)v >> 6) & 0xFFu;
    for (int c = 0; c < 8; ++c) if ((hb >> c) & 1u) r ^= s.Lc[c];
    return r & 7u;
}
static int rank3(const unsigned* q, int n) {
    unsigned bas[3] = {0, 0, 0};
    int r = 0;
    for (int j = 0; j < n; ++j) {
        unsigned v = q[j];
        for (int bit = 2; bit >= 0; --bit) {
            if (!((v >> bit) & 1u)) continue;
            if (bas[bit]) { v ^= bas[bit]; continue; }
            bas[bit] = v; ++r; v = 0; break;
        }
    }
    return r;
}
static bool minv_ok(unsigned c4, unsigned c5) {  // {e0, c4, c5} rank 3
    const unsigned q[3] = {1u, c4 & 7u, c5 & 7u};
    return rank3(q, 3) == 3;
}
static int score_swz(const SwzP& s, const u16 MmRaw[NPASS][4]) {
    int bad = 0;
    for (int p = 0; p < NPASS; ++p) {
        unsigned q[4];
        for (int j = 0; j < 4; ++j) q[j] = proj35(s, MmRaw[p][j]);
        bad += 3 - rank3(q, 4);
    }
    return bad;
}
static GFm A_from(const SwzP& s) {
    GFm A;
    for (int b = 0; b < 14; ++b) A.col[b] = (u16)(1u << b);
    A.col[4] = (u16)((s.c4 & 7u) << 3);
    A.col[5] = (u16)((s.c5 & 7u) << 3);
    for (int c = 0; c < 8; ++c)
        A.col[6 + c] = (u16)((1u << (6 + c)) ^ (((unsigned)s.Lc[c] & 7u) << 3));
    return A;
}
static void choose_swz(const Plan& raw, GFm& A, GFm& Ainv) {
    u16 MmRaw[NPASS][4];
    for (int p = 0; p < NPASS; ++p)
        for (int j = 0; j < 4; ++j) MmRaw[p][j] = raw.ps[p].Mm[j];

    // candidate 0 = the long-standing fixed hash (baseline)
    SwzP best = {2u, 4u, {1, 2, 4, 1, 2, 5, 2, 4}};
    int bestScore = score_swz(best, MmRaw);

    uint64_t rng = 0x9E3779B97F4A7C15ull;
    auto rnd = [&]() -> unsigned {
        rng = rng * 6364136223846793005ull + 1442695040888963407ull;
        return (unsigned)(rng >> 33);
    };
    for (int t = 0; t < 8000 && bestScore > 0; ++t) {
        SwzP s;
        s.c4 = rnd() & 7u; s.c5 = rnd() & 7u;
        if (!minv_ok(s.c4, s.c5)) continue;
        for (int c = 0; c < 8; ++c) s.Lc[c] = (unsigned char)(rnd() & 7u);
        const int sc = score_swz(s, MmRaw);
        if (sc < bestScore) { bestScore = sc; best = s; }
    }
    A = A_from(best);
    Ainv = gf_inv(A);
}
static void fold_A(Plan& pl, const GFm& A, const GFm& Ainv) {
    for (int p = 0; p < NPASS; ++p) {
        for (int j = 0; j < 4; ++j) pl.ps[p].Mm[j] = gf_apply(A, pl.ps[p].Mm[j]);
        for (int j = 0; j < 3; ++j) pl.ps[p].Mt[j] = gf_apply(A, pl.ps[p].Mt[j]);
        for (int j = 0; j < 3; ++j) pl.ps[p].Mw[j] = gf_apply(A, pl.ps[p].Mw[j]);
    }
    for (int b = 0; b < 14; ++b) pl.initM[b] = gf_apply(A, pl.initM[b]);
    // sign(storage s) = parity(r . logical), logical = Ainv(s)
    //   => measR'_b = parity(r & Ainv.col[b])
    const unsigned r = pl.measR;
    u16 nr = 0;
    for (int b = 0; b < 14; ++b)
        if (__builtin_popcount(r & (unsigned)Ainv.col[b]) & 1) nr |= (u16)(1u << b);
    pl.measR = nr;
}

extern "C" void kernel_launch(void* const* d_in, const int* in_sizes, int n_in,
                              void* d_out, int out_size, void* d_ws, size_t ws_size,
                              hipStream_t stream) {
    const float* x_raw  = (const float*)d_in[0];
    const float* angles = (const float*)d_in[1];
    float* out = (float*)d_out;
    const int bsz = in_sizes[0] / NW;

    Plan pl;
    build_plan(pl);
    GFm A, Ainv;
    choose_swz(pl, A, Ainv);
    fold_A(pl, A, Ainv);

    // d_ws layout: [0,24576) dual W tables (f16, per q-half), then layer-0 gates
    f16*    wt_g = (f16*)d_ws;
    float2* u0_g = (float2*)((char*)d_ws + (size_t)2 * NPASS * WTP * sizeof(f16));

    vqc_pre<<<dim3(1), dim3(PRETHR), 0, stream>>>(angles, wt_g, u0_g);

    // LDS: 64K state + 224B G0c + 32B red = 65792 B -> 2 blocks/CU
    const size_t lds = (size_t)2 * NST * sizeof(f16)
                     + (size_t)(2 * NW) * sizeof(float2)
                     + (size_t)(THREADS / 64) * sizeof(float);
    (void)hipFuncSetAttribute((const void*)vqc_kernel,
                              hipFuncAttributeMaxDynamicSharedMemorySize, (int)lds);
    vqc_kernel<<<dim3(bsz), dim3(THREADS), lds, stream>>>(x_raw, wt_g, u0_g, out, pl);
}